// Round 5
// baseline (5366.836 us; speedup 1.0000x reference)
//
#include <hip/hip_runtime.h>
#include <math.h>

#define Bq 512
#define Tq 64
#define Hq 450
#define Lq 56
#define Vq 780
#define Mq 8
#define TBq 32768
#define Sq 32770
#define HP 480          // bf16 row stride (mult of 32)
#define F32S 464        // f32 row stride
#define NPB 130         // 130*256 = 33280 rows
#define NPCAP 12288     // compacted pred rows cap
#define NSCAP 20480     // compacted stop rows cap
#define CH2 4096        // pred score chunk rows
#define NCH2 3
#define NBLK 32         // persistent scan grid

using bf16x8 = __attribute__((ext_vector_type(8))) __bf16;
using f32x4  = __attribute__((ext_vector_type(4))) float;

__device__ __forceinline__ ushort f2bf(float f){
    union { float f; unsigned u; } c; c.f = f;
    unsigned u = c.u;
    return (ushort)((u + 0x7FFFu + ((u >> 16) & 1u)) >> 16);
}
__device__ __forceinline__ float bf2f(ushort h){
    union { unsigned u; float f; } c; c.u = ((unsigned)h) << 16;
    return c.f;
}
__device__ __forceinline__ unsigned pk2(float a, float b){
    return (unsigned)f2bf(a) | ((unsigned)f2bf(b) << 16);
}
__device__ __forceinline__ float sigmf(float x){
    return __builtin_amdgcn_rcpf(1.f + __expf(-x));
}
__device__ __forceinline__ float tanhfast(float x){
    float e2 = __expf(2.f * x);
    return 1.f - 2.f * __builtin_amdgcn_rcpf(e2 + 1.f);
}

// ---------- device-scope grid barrier (32 co-resident blocks) ----------
__device__ __forceinline__ void gbar(int* bar){
    __syncthreads();
    if (threadIdx.x == 0){
        int gen = __hip_atomic_load(&bar[1], __ATOMIC_RELAXED, __HIP_MEMORY_SCOPE_AGENT);
        int old = __hip_atomic_fetch_add(&bar[0], 1, __ATOMIC_ACQ_REL, __HIP_MEMORY_SCOPE_AGENT);
        if (old == NBLK - 1){
            __hip_atomic_store(&bar[0], 0, __ATOMIC_RELAXED, __HIP_MEMORY_SCOPE_AGENT);
            __hip_atomic_store(&bar[1], gen + 1, __ATOMIC_RELEASE, __HIP_MEMORY_SCOPE_AGENT);
        } else {
            while (__hip_atomic_load(&bar[1], __ATOMIC_RELAXED, __HIP_MEMORY_SCOPE_AGENT) == gen)
                __builtin_amdgcn_s_sleep(1);
            (void)__hip_atomic_load(&bar[1], __ATOMIC_ACQUIRE, __HIP_MEMORY_SCOPE_AGENT);
        }
    }
    __syncthreads();
}

// ---------- fused converter: 14 jobs by blockIdx.y ----------
__global__ void convAll_k(
    const float* __restrict__ emb, const float* __restrict__ tree,
    const float* __restrict__ Wz, const float* __restrict__ Wr,
    const float* __restrict__ Ur, const float* __restrict__ Wh,
    const float* __restrict__ Wm, const float* __restrict__ U, const float* __restrict__ Wo,
    ushort* embb, ushort* treeb, ushort* WzX, ushort* WzS, ushort* WrB,
    ushort* WhX, ushort* WhG, ushort* UrB, ushort* WHp, ushort* UXp,
    ushort* UOp, ushort* WOp, ushort* WLp, ushort* ULp)
{
    int job = blockIdx.y, n = blockIdx.x;
    const float* src; ushort* dst; int Npad, Nsrc, Ksrc, Kpad, len, off;
    switch(job){
      case 0:  src=emb;  dst=embb; Npad=896; Nsrc=780; Ksrc=450; Kpad=480; len=450; off=0;   break;
      case 1:  src=tree; dst=treeb;Npad=512; Nsrc=512; Ksrc=56;  Kpad=64;  len=56;  off=0;   break;
      case 2:  src=Wz;   dst=WzX;  Npad=512; Nsrc=450; Ksrc=900; Kpad=480; len=450; off=0;   break;
      case 3:  src=Wz;   dst=WzS;  Npad=512; Nsrc=450; Ksrc=900; Kpad=480; len=450; off=450; break;
      case 4:  src=Wr;   dst=WrB;  Npad=512; Nsrc=450; Ksrc=450; Kpad=480; len=450; off=0;   break;
      case 5:  src=Wh;   dst=WhX;  Npad=512; Nsrc=450; Ksrc=900; Kpad=480; len=450; off=0;   break;
      case 6:  src=Wh;   dst=WhG;  Npad=512; Nsrc=450; Ksrc=900; Kpad=480; len=450; off=450; break;
      case 7:  src=Ur;   dst=UrB;  Npad=512; Nsrc=450; Ksrc=450; Kpad=480; len=450; off=0;   break;
      case 8:  src=Wm;   dst=WHp;  Npad=512; Nsrc=450; Ksrc=506; Kpad=480; len=450; off=0;   break;
      case 9:  src=U;    dst=UXp;  Npad=512; Nsrc=450; Ksrc=956; Kpad=480; len=450; off=0;   break;
      case 10: src=U;    dst=UOp;  Npad=512; Nsrc=450; Ksrc=956; Kpad=480; len=450; off=450; break;
      case 11: src=Wo;   dst=WOp;  Npad=832; Nsrc=780; Ksrc=450; Kpad=480; len=450; off=0;   break;
      case 12: src=Wm;   dst=WLp;  Npad=512; Nsrc=450; Ksrc=506; Kpad=64;  len=56;  off=450; break;
      default: src=U;    dst=ULp;  Npad=512; Nsrc=450; Ksrc=956; Kpad=64;  len=56;  off=900; break;
    }
    if (n >= Npad) return;
    for (int k = threadIdx.x; k < Kpad; k += blockDim.x){
        float v = 0.f;
        if (n < Nsrc && k < len) v = src[(size_t)n*Ksrc + off + k];
        dst[(size_t)n*Kpad + k] = f2bf(v);
    }
}

// ---------- double-buffered MFMA GEMM body: C(128x64) tile ----------
template<class APtr>
__device__ __forceinline__ void mgemm2(APtr&& aptr, const ushort* __restrict__ Bw, int ldb,
                                       int KT, int col0, f32x4 acc[4][2])
{
    __shared__ __align__(16) char As[2][128*80];
    __shared__ __align__(16) char Bs[2][64*80];
    const int tid = threadIdx.x;
    const int lane = tid & 63;
    const int w = tid >> 6, wm = w >> 1, wn = w & 1;
    const int ac = (tid & 3) * 8;
    const size_t boff = (size_t)(col0 + (tid >> 2)) * ldb;
    uint4 ra0, ra1, rb;
    auto ld = [&](int k0){
        ra0 = *(const uint4*)(aptr(0, k0) + ac);
        ra1 = *(const uint4*)(aptr(1, k0) + ac);
        rb  = *(const uint4*)(Bw + boff + k0 + ac);
    };
    const int wr_a0 = (tid>>2)*80 + (tid&3)*16;
    const int wr_a1 = ((tid>>2)+64)*80 + (tid&3)*16;
    const int wr_b  = (tid>>2)*80 + (tid&3)*16;
    const int rd_a  = (wm*64 + (lane&15))*80 + (lane>>4)*16;
    const int rd_b  = (wn*32 + (lane&15))*80 + (lane>>4)*16;
    ld(0);
    *(uint4*)(As[0]+wr_a0) = ra0; *(uint4*)(As[0]+wr_a1) = ra1; *(uint4*)(Bs[0]+wr_b) = rb;
#pragma unroll
    for (int f=0;f<4;f++)
#pragma unroll
        for (int g=0;g<2;g++) acc[f][g] = (f32x4){0.f,0.f,0.f,0.f};
    __syncthreads();
    for (int kt=0; kt<KT; ++kt){
        const int cur = kt & 1;
        if (kt+1 < KT) ld((kt+1)*32);
        bf16x8 bF[2];
#pragma unroll
        for (int g=0; g<2; g++) bF[g] = *(const bf16x8*)(Bs[cur] + rd_b + g*16*80);
#pragma unroll
        for (int f=0; f<4; f++){
            bf16x8 aF = *(const bf16x8*)(As[cur] + rd_a + f*16*80);
#pragma unroll
            for (int g=0; g<2; g++)
                acc[f][g] = __builtin_amdgcn_mfma_f32_16x16x32_bf16(aF, bF[g], acc[f][g], 0, 0, 0);
        }
        if (kt+1 < KT){
            *(uint4*)(As[cur^1]+wr_a0) = ra0; *(uint4*)(As[cur^1]+wr_a1) = ra1;
            *(uint4*)(Bs[cur^1]+wr_b) = rb;
        }
        __syncthreads();
    }
}

#define EPI_PRE  const int lane = threadIdx.x & 63; const int w_ = threadIdx.x >> 6; \
                 const int wm = w_ >> 1, wn = w_ & 1;

// ---------- precompute GEMM body ----------
__device__ __forceinline__ void pre_body(const ushort* __restrict__ A, int lda,
    const ushort* __restrict__ Bw, const float* __restrict__ bias,
    float* __restrict__ out, int Mr, int KT)
{
    const int row0 = blockIdx.y*128, col0 = blockIdx.x*64;
    const int tid = threadIdx.x;
    const ushort* p0 = A + (size_t)(row0 + (tid>>2))*lda;
    const ushort* p1 = p0 + (size_t)64*lda;
    f32x4 acc[4][2];
    mgemm2([&](int which,int k0){ return (which?p1:p0)+k0; }, Bw, lda, KT, col0, acc);
    EPI_PRE
#pragma unroll
    for (int f=0; f<4; f++)
#pragma unroll
      for (int g=0; g<2; g++){
        int col = col0 + wn*32 + g*16 + (lane & 15);
        if (col >= F32S) continue;
        float bb = 0.f;
        if (col < Hq && bias) bb = bias[col];
#pragma unroll
        for (int j=0; j<4; j++){
            int row = row0 + wm*64 + f*16 + ((lane>>4)<<2) + j;
            if (row < Mr) out[(size_t)row*F32S + col] = (col < Hq) ? acc[f][g][j] + bb : 0.f;
        }
      }
}

__global__ __launch_bounds__(256) void preE_k(
    const ushort* __restrict__ embb,
    const ushort* __restrict__ WzX, const ushort* __restrict__ WrB,
    const ushort* __restrict__ WhX, const ushort* __restrict__ UXp,
    const float* __restrict__ bz, const float* __restrict__ br,
    const float* __restrict__ bh, const float* __restrict__ bU,
    float* __restrict__ EZ, float* __restrict__ ER,
    float* __restrict__ EH, float* __restrict__ EU)
{
    const ushort* Bw; const float* bias; float* out;
    switch(blockIdx.z){
      case 0:  Bw=WzX; bias=bz; out=EZ; break;
      case 1:  Bw=WrB; bias=br; out=ER; break;
      case 2:  Bw=WhX; bias=bh; out=EH; break;
      default: Bw=UXp; bias=bU; out=EU; break;
    }
    pre_body(embb, HP, Bw, bias, out, Vq, 15);
}

__global__ __launch_bounds__(256) void preT_k(
    const ushort* __restrict__ treeb,
    const ushort* __restrict__ WLp, const ushort* __restrict__ ULp,
    const float* __restrict__ bW, float* __restrict__ TP, float* __restrict__ TU)
{
    const ushort* Bw = blockIdx.z ? ULp : WLp;
    const float* bias = blockIdx.z ? nullptr : bW;
    float* out = blockIdx.z ? TU : TP;
    pre_body(treeb, 64, Bw, bias, out, Bq, 2);
}

// ---------- compaction: count / scan / fill ----------
__device__ __forceinline__ bool cmask(int which, int gr,
    const int* __restrict__ valid, const int* __restrict__ dir)
{
    if (which == 0) return (gr < Bq) ? true : (valid[gr-Bq] && dir[gr-Bq]);
    return (gr < TBq) ? (valid[gr] != 0) : true;
}
__global__ void cnt_k(const int* __restrict__ valid, const int* __restrict__ dir,
                      int* __restrict__ cnts)
{
    int which = blockIdx.y;
    int gr = blockIdx.x*256 + threadIdx.x;
    bool m = cmask(which, gr, valid, dir);
    unsigned long long bal = __ballot(m);
    if ((threadIdx.x & 63) == 0)
        atomicAdd(&cnts[which*NPB + blockIdx.x], (int)__popcll(bal));
}
__global__ void scan_k(const int* __restrict__ cnts, int* __restrict__ offs,
                       int* __restrict__ totals)
{
    if (threadIdx.x == 0){
        int a = 0;
        for (int i=0;i<NPB;i++){ offs[i] = a; a += cnts[i]; }
        totals[0] = a;
        int b = 0;
        for (int i=0;i<NPB;i++){ offs[NPB+i] = b; b += cnts[NPB+i]; }
        totals[1] = b;
    }
}
__global__ void fill_k(const int* __restrict__ valid, const int* __restrict__ dir,
                       const int* __restrict__ offs, int* __restrict__ listp,
                       int* __restrict__ lists)
{
    __shared__ int woff[4];
    int which = blockIdx.y;
    int gr = blockIdx.x*256 + threadIdx.x;
    bool m = cmask(which, gr, valid, dir);
    unsigned long long bal = __ballot(m);
    int lane = threadIdx.x & 63, wv = threadIdx.x >> 6;
    if (lane == 0) woff[wv] = (int)__popcll(bal);
    __syncthreads();
    int prev = 0;
    for (int i=0;i<wv;i++) prev += woff[i];
    if (m){
        int rank = prev + (int)__popcll(bal & ((1ull << lane) - 1ull));
        int pos = offs[which*NPB + blockIdx.x] + rank;
        if (which == 0){ if (pos < NPCAP) listp[pos] = gr; }
        else           { if (pos < NSCAP) lists[pos] = gr; }
    }
}

// ---------- persistent scan: 64 steps, 3 phases/step, grid barrier ----------
__global__ __launch_bounds__(256, 1) void scan_coop(
    const int* __restrict__ x_wid, const int* __restrict__ h_nei_idx,
    const int* __restrict__ valid,
    const float* __restrict__ ER, const float* __restrict__ EZ, const float* __restrict__ EH,
    const ushort* __restrict__ WzS, const ushort* __restrict__ WhG, const ushort* __restrict__ UrB,
    ushort* __restrict__ hbuf, ushort* __restrict__ uhbuf,
    ushort* __restrict__ sumh, ushort* __restrict__ gated, ushort* __restrict__ nh,
    int* __restrict__ bar)
{
    __shared__ __align__(16) char smem[61440];
    const int tid = threadIdx.x;
    const int blk = blockIdx.x;
    const int lane = tid & 63;
    const int wv = tid >> 6, wm = wv >> 1, wn = wv & 1;
    const int row0 = (blk >> 3) * 128;   // GEMM tile row
    const int col0 = (blk & 7) * 64;     // GEMM tile col

    for (int t = 0; t < Tq; ++t){
        // ======== phase A: gather sum_h & gated for rows blk*16..+16 ========
        {
            const int j0 = lane * 8;
            const int rsub = tid >> 6;
            if (j0 < HP){
                for (int p = 0; p < 4; ++p){
                    const int b = blk*16 + p*4 + rsub;
                    const int base = t*Bq + b;
                    uint4 so, go;
                    if (j0 < 456){
                        const int wid = x_wid[base];
                        const int* ip = h_nei_idx + (size_t)base*Mq;
                        float er[8];
                        const float* erp = ER + (size_t)wid*F32S + j0;
#pragma unroll
                        for (int e=0;e<8;e++) er[e] = erp[e];
                        float sh[8] = {0,0,0,0,0,0,0,0};
                        float gt[8] = {0,0,0,0,0,0,0,0};
#pragma unroll
                        for (int m=0;m<Mq;m++){
                            int ix = ip[m];
                            uint4 hv = *(const uint4*)(hbuf  + (size_t)ix*HP + j0);
                            uint4 uv = *(const uint4*)(uhbuf + (size_t)ix*HP + j0);
                            unsigned hw[4] = {hv.x,hv.y,hv.z,hv.w};
                            unsigned uw[4] = {uv.x,uv.y,uv.z,uv.w};
#pragma unroll
                            for (int e=0;e<8;e++){
                                float h = bf2f((ushort)((hw[e>>1] >> ((e&1)*16)) & 0xffff));
                                float u = bf2f((ushort)((uw[e>>1] >> ((e&1)*16)) & 0xffff));
                                sh[e] += h;
                                gt[e] += h * sigmf(er[e] + u);
                            }
                        }
                        so.x = pk2(sh[0],sh[1]); so.y = pk2(sh[2],sh[3]);
                        so.z = pk2(sh[4],sh[5]); so.w = pk2(sh[6],sh[7]);
                        go.x = pk2(gt[0],gt[1]); go.y = pk2(gt[2],gt[3]);
                        go.z = pk2(gt[4],gt[5]); go.w = pk2(gt[6],gt[7]);
                    } else {
                        so = (uint4){0,0,0,0}; go = (uint4){0,0,0,0};
                    }
                    *(uint4*)(sumh  + (size_t)b*HP + j0) = so;
                    *(uint4*)(gated + (size_t)b*HP + j0) = go;
                }
            }
        }
        gbar(bar);
        // ======== phase B: twin GEMM (z,h) + GRU blend ========
        {
            char* Az = smem;            // 2 x 10240
            char* Ag = smem + 20480;    // 2 x 10240
            char* Bz = smem + 40960;    // 2 x 5120
            char* Bg = smem + 51200;    // 2 x 5120
            const int ar = tid >> 2, acf = (tid & 3) * 8;
            const ushort* pz0 = sumh  + (size_t)(row0+ar)*HP;
            const ushort* pz1 = pz0 + (size_t)64*HP;
            const ushort* pg0 = gated + (size_t)(row0+ar)*HP;
            const ushort* pg1 = pg0 + (size_t)64*HP;
            const ushort* qz  = WzS + (size_t)(col0+ar)*HP;
            const ushort* qg  = WhG + (size_t)(col0+ar)*HP;
            const int wrA0 = ar*80 + (tid&3)*16;
            const int wrA1 = (ar+64)*80 + (tid&3)*16;
            const int wrB  = ar*80 + (tid&3)*16;
            const int rdA  = (wm*64 + (lane&15))*80 + (lane>>4)*16;
            const int rdB  = (wn*32 + (lane&15))*80 + (lane>>4)*16;
            uint4 rz0,rz1,rg0,rg1,szr,sgr;
            f32x4 az[4][2], ah[4][2];
#pragma unroll
            for (int f=0;f<4;f++)
#pragma unroll
                for (int g=0;g<2;g++){ az[f][g]=(f32x4){0,0,0,0}; ah[f][g]=(f32x4){0,0,0,0}; }
            rz0 = *(const uint4*)(pz0 + acf); rz1 = *(const uint4*)(pz1 + acf);
            rg0 = *(const uint4*)(pg0 + acf); rg1 = *(const uint4*)(pg1 + acf);
            szr = *(const uint4*)(qz + acf);  sgr = *(const uint4*)(qg + acf);
            *(uint4*)(Az + wrA0) = rz0; *(uint4*)(Az + wrA1) = rz1;
            *(uint4*)(Ag + wrA0) = rg0; *(uint4*)(Ag + wrA1) = rg1;
            *(uint4*)(Bz + wrB) = szr;  *(uint4*)(Bg + wrB) = sgr;
            __syncthreads();
            for (int kt=0; kt<15; ++kt){
                const int cur = kt & 1;
                const int cA = cur*10240, cB = cur*5120;
                if (kt < 14){
                    int k0 = (kt+1)*32;
                    rz0 = *(const uint4*)(pz0 + k0 + acf); rz1 = *(const uint4*)(pz1 + k0 + acf);
                    rg0 = *(const uint4*)(pg0 + k0 + acf); rg1 = *(const uint4*)(pg1 + k0 + acf);
                    szr = *(const uint4*)(qz + k0 + acf);  sgr = *(const uint4*)(qg + k0 + acf);
                }
                bf16x8 bz_[2], bg_[2];
#pragma unroll
                for (int g=0; g<2; g++){
                    bz_[g] = *(const bf16x8*)(Bz + cB + rdB + g*16*80);
                    bg_[g] = *(const bf16x8*)(Bg + cB + rdB + g*16*80);
                }
#pragma unroll
                for (int f=0; f<4; f++){
                    bf16x8 aFz = *(const bf16x8*)(Az + cA + rdA + f*16*80);
                    bf16x8 aFg = *(const bf16x8*)(Ag + cA + rdA + f*16*80);
#pragma unroll
                    for (int g=0; g<2; g++){
                        az[f][g] = __builtin_amdgcn_mfma_f32_16x16x32_bf16(aFz, bz_[g], az[f][g], 0, 0, 0);
                        ah[f][g] = __builtin_amdgcn_mfma_f32_16x16x32_bf16(aFg, bg_[g], ah[f][g], 0, 0, 0);
                    }
                }
                if (kt < 14){
                    const int nA = (cur^1)*10240, nB = (cur^1)*5120;
                    *(uint4*)(Az + nA + wrA0) = rz0; *(uint4*)(Az + nA + wrA1) = rz1;
                    *(uint4*)(Ag + nA + wrA0) = rg0; *(uint4*)(Ag + nA + wrA1) = rg1;
                    *(uint4*)(Bz + nB + wrB) = szr;  *(uint4*)(Bg + nB + wrB) = sgr;
                }
                __syncthreads();
            }
#pragma unroll
            for (int f=0; f<4; f++)
#pragma unroll
              for (int g=0; g<2; g++){
                int col = col0 + wn*32 + g*16 + (lane & 15);
                if (col >= Hq) continue;
#pragma unroll
                for (int j=0; j<4; j++){
                    int b = row0 + wm*64 + f*16 + ((lane>>4)<<2) + j;
                    int base = t*Bq + b;
                    int wid = x_wid[base];
                    float z  = sigmf(az[f][g][j] + EZ[(size_t)wid*F32S + col]);
                    float ht = tanhfast(ah[f][g][j] + EH[(size_t)wid*F32S + col]);
                    float sh = bf2f(sumh[(size_t)b*HP + col]);
                    ushort o = f2bf((1.f - z)*sh + z*ht);
                    nh[(size_t)b*HP + col] = o;
                    if (valid[base]) hbuf[(size_t)(1 + base)*HP + col] = o;
                }
              }
        }
        gbar(bar);
        // ======== phase C: uh = nh @ Ur^T ========
        {
            char* As = smem;            // 2 x 10240
            char* Bs = smem + 20480;    // 2 x 5120
            const int ar = tid >> 2, acf = (tid & 3) * 8;
            const ushort* a0 = nh + (size_t)(row0+ar)*HP;
            const ushort* a1 = a0 + (size_t)64*HP;
            const ushort* bqp = UrB + (size_t)(col0+ar)*HP;
            const int wrA0 = ar*80 + (tid&3)*16;
            const int wrA1 = (ar+64)*80 + (tid&3)*16;
            const int wrB  = ar*80 + (tid&3)*16;
            const int rdA  = (wm*64 + (lane&15))*80 + (lane>>4)*16;
            const int rdB  = (wn*32 + (lane&15))*80 + (lane>>4)*16;
            uint4 ra0, ra1, rb;
            f32x4 acc[4][2];
#pragma unroll
            for (int f=0;f<4;f++)
#pragma unroll
                for (int g=0;g<2;g++) acc[f][g] = (f32x4){0,0,0,0};
            ra0 = *(const uint4*)(a0 + acf); ra1 = *(const uint4*)(a1 + acf);
            rb  = *(const uint4*)(bqp + acf);
            *(uint4*)(As + wrA0) = ra0; *(uint4*)(As + wrA1) = ra1; *(uint4*)(Bs + wrB) = rb;
            __syncthreads();
            for (int kt=0; kt<15; ++kt){
                const int cur = kt & 1;
                const int cA = cur*10240, cB = cur*5120;
                if (kt < 14){
                    int k0 = (kt+1)*32;
                    ra0 = *(const uint4*)(a0 + k0 + acf); ra1 = *(const uint4*)(a1 + k0 + acf);
                    rb  = *(const uint4*)(bqp + k0 + acf);
                }
                bf16x8 bF[2];
#pragma unroll
                for (int g=0; g<2; g++) bF[g] = *(const bf16x8*)(Bs + cB + rdB + g*16*80);
#pragma unroll
                for (int f=0; f<4; f++){
                    bf16x8 aF = *(const bf16x8*)(As + cA + rdA + f*16*80);
#pragma unroll
                    for (int g=0; g<2; g++)
                        acc[f][g] = __builtin_amdgcn_mfma_f32_16x16x32_bf16(aF, bF[g], acc[f][g], 0, 0, 0);
                }
                if (kt < 14){
                    const int nA = (cur^1)*10240, nB = (cur^1)*5120;
                    *(uint4*)(As + nA + wrA0) = ra0; *(uint4*)(As + nA + wrA1) = ra1;
                    *(uint4*)(Bs + nB + wrB) = rb;
                }
                __syncthreads();
            }
#pragma unroll
            for (int f=0; f<4; f++)
#pragma unroll
              for (int g=0; g<2; g++){
                int col = col0 + wn*32 + g*16 + (lane & 15);
                if (col >= Hq) continue;
#pragma unroll
                for (int j=0; j<4; j++){
                    int b = row0 + wm*64 + f*16 + ((lane>>4)<<2) + j;
                    int base = t*Bq + b;
                    if (valid[base]) uhbuf[(size_t)(1 + base)*HP + col] = f2bf(acc[f][g][j]);
                }
              }
        }
        gbar(bar);
    }
}

// ---------- pred GEMM1 (compacted rows) ----------
__global__ __launch_bounds__(256) void pred1c_k(const int* __restrict__ np_,
    const int* __restrict__ listp, const ushort* __restrict__ hbuf,
    const float* __restrict__ TP, const ushort* __restrict__ WHp,
    ushort* __restrict__ pv)
{
    const int np = *np_;
    const int row0 = blockIdx.y*128;
    if (row0 >= np) return;
    const int col0 = blockIdx.x*64;
    const int tid = threadIdx.x;
    int i0 = row0 + (tid>>2), i1 = i0 + 64;
    int g0 = (i0 < np) ? listp[i0] : 0;
    int g1 = (i1 < np) ? listp[i1] : 0;
    const ushort* p0 = (g0 < Bq) ? hbuf : hbuf + (size_t)(1 + g0 - Bq)*HP;  // hbuf row0 = zeros
    const ushort* p1 = (g1 < Bq) ? hbuf : hbuf + (size_t)(1 + g1 - Bq)*HP;
    f32x4 acc[4][2];
    mgemm2([&](int which,int k0){ return (which?p1:p0)+k0; }, WHp, HP, 15, col0, acc);
    EPI_PRE
#pragma unroll
    for (int f=0; f<4; f++)
#pragma unroll
      for (int g=0; g<2; g++){
        int col = col0 + wn*32 + g*16 + (lane & 15);
        if (col >= HP) continue;
#pragma unroll
        for (int j=0; j<4; j++){
            int i = row0 + wm*64 + f*16 + ((lane>>4)<<2) + j;
            if (i >= np) continue;
            int gr = listp[i];
            int b = (gr < Bq) ? gr : ((gr - Bq) & (Bq-1));
            float v = 0.f;
            if (col < Hq) v = fmaxf(acc[f][g][j] + TP[(size_t)b*F32S + col], 0.f);
            pv[(size_t)i*HP + col] = f2bf(v);
        }
      }
}

// ---------- pred GEMM2 ----------
__global__ __launch_bounds__(256) void pred2c_k(int cs, const int* __restrict__ np_,
    const ushort* __restrict__ pv, const ushort* __restrict__ WOp,
    const float* __restrict__ bWo, float* __restrict__ scores)
{
    const int np = *np_;
    const int row0 = blockIdx.y*128;
    if (cs + row0 >= np) return;
    const int col0 = blockIdx.x*64;
    const int tid = threadIdx.x;
    const ushort* p0 = pv + (size_t)(cs + row0 + (tid>>2))*HP;
    const ushort* p1 = p0 + (size_t)64*HP;
    f32x4 acc[4][2];
    mgemm2([&](int which,int k0){ return (which?p1:p0)+k0; }, WOp, HP, 15, col0, acc);
    EPI_PRE
#pragma unroll
    for (int f=0; f<4; f++)
#pragma unroll
      for (int g=0; g<2; g++){
        int col = col0 + wn*32 + g*16 + (lane & 15);
        if (col >= Vq) continue;
        float bc = bWo[col];
#pragma unroll
        for (int j=0; j<4; j++){
            int r = row0 + wm*64 + f*16 + ((lane>>4)<<2) + j;
            scores[(size_t)r*832 + col] = acc[f][g][j] + bc;
        }
      }
}

// ---------- pred reduce: wave-per-row ----------
__global__ __launch_bounds__(256) void predred_k(int cs, const int* __restrict__ np_,
    const int* __restrict__ listp, const float* __restrict__ scores,
    const int* __restrict__ pred_wid, const int* __restrict__ root_wid,
    float* __restrict__ accv)
{
    const int np = *np_;
    int nrows = np - cs; if (nrows > CH2) nrows = CH2;
    const int lane = threadIdx.x & 63, wv = threadIdx.x >> 6;
    const int wid_g = blockIdx.x*4 + wv, nw = gridDim.x*4;
    float ce = 0.f, hit = 0.f, cnt = 0.f;
    for (int r = wid_g; r < nrows; r += nw){
        const float* sc = scores + (size_t)r*832;
        int gr = listp[cs + r];
        int tgt = (gr < Bq) ? root_wid[gr] : pred_wid[gr - Bq];
        float vals[13];
        float bv = -INFINITY, tv = 0.f; int bi = 0;
#pragma unroll
        for (int q=0; q<13; q++){
            int j = lane + q*64;
            float v = (j < Vq) ? sc[j] : -INFINITY;
            vals[q] = v;
            if (v > bv){ bv = v; bi = j; }
            if (j == tgt) tv = v;
        }
#pragma unroll
        for (int off=32; off; off>>=1){
            float ov = __shfl_xor(bv, off); int oi = __shfl_xor(bi, off);
            if (ov > bv || (ov == bv && oi < bi)){ bv = ov; bi = oi; }
        }
        float s = 0.f;
#pragma unroll
        for (int q=0; q<13; q++){
            int j = lane + q*64;
            if (j < Vq) s += __expf(vals[q] - bv);
        }
#pragma unroll
        for (int off=32; off; off>>=1) s += __shfl_xor(s, off);
#pragma unroll
        for (int off=32; off; off>>=1) tv += __shfl_xor(tv, off);
        if (lane == 0){
            ce += bv + logf(s) - tv;
            hit += (bi == tgt) ? 1.f : 0.f;
            cnt += 1.f;
        }
    }
    __shared__ float L[3][4];
    if (lane == 0){ L[0][wv] = ce; L[1][wv] = hit; L[2][wv] = cnt; }
    __syncthreads();
    if (threadIdx.x == 0){
        float a = L[0][0]+L[0][1]+L[0][2]+L[0][3];
        float b = L[1][0]+L[1][1]+L[1][2]+L[1][3];
        float c = L[2][0]+L[2][1]+L[2][2]+L[2][3];
        if (c != 0.f){
            atomicAdd(&accv[0], a);
            atomicAdd(&accv[1], b);
            atomicAdd(&accv[2], c);
        }
    }
}

// ---------- stop: cur_o gather (compacted) ----------
__global__ void curo_c(const int* __restrict__ ns_, const int* __restrict__ lists,
                       const int* __restrict__ o_nei_idx, const int* __restrict__ root_o_nei,
                       const ushort* __restrict__ hbuf, ushort* __restrict__ curo)
{
    int i = blockIdx.x;
    if (i >= *ns_) return;
    int gr = lists[i];
    int j0 = threadIdx.x * 4;
    if (j0 >= HP) return;
    int idx[Mq];
    if (gr < TBq){
        int tt = gr >> 9;
#pragma unroll
        for (int m=0;m<Mq;m++){
            int ix = o_nei_idx[(size_t)gr*Mq + m];
            idx[m] = (ix <= tt*Bq) ? ix : 0;   // slots written before step tt; row 0 is zero
        }
    } else {
#pragma unroll
        for (int m=0;m<Mq;m++) idx[m] = root_o_nei[(size_t)(gr-TBq)*Mq + m];
    }
    float s0=0,s1=0,s2=0,s3=0;
#pragma unroll
    for (int m=0;m<Mq;m++){
        uint2 v = *(const uint2*)(hbuf + (size_t)idx[m]*HP + j0);
        s0 += bf2f((ushort)(v.x & 0xffff)); s1 += bf2f((ushort)(v.x >> 16));
        s2 += bf2f((ushort)(v.y & 0xffff)); s3 += bf2f((ushort)(v.y >> 16));
    }
    uint2 o; o.x = pk2(s0, s1); o.y = pk2(s2, s3);
    *(uint2*)(curo + (size_t)i*HP + j0) = o;
}

// ---------- stop GEMM (compacted) + fused Us-dot ----------
__global__ __launch_bounds__(256) void stopc_k(const int* __restrict__ ns_,
    const int* __restrict__ lists, const int* __restrict__ x_wid,
    const int* __restrict__ root_wid, const ushort* __restrict__ curo,
    const ushort* __restrict__ UOp, const float* __restrict__ EU,
    const float* __restrict__ TU, const float* __restrict__ Usf,
    float* __restrict__ ss)
{
    const int ns = *ns_;
    const int row0 = blockIdx.y*128;
    if (row0 >= ns) return;
    const int col0 = blockIdx.x*64;
    const int tid = threadIdx.x;
    const ushort* p0 = curo + (size_t)(row0 + (tid>>2))*HP;
    const ushort* p1 = p0 + (size_t)64*HP;
    f32x4 acc[4][2];
    mgemm2([&](int which,int k0){ return (which?p1:p0)+k0; }, UOp, HP, 15, col0, acc);
    EPI_PRE
#pragma unroll
    for (int f=0; f<4; f++){
#pragma unroll
        for (int j=0; j<4; j++){
            int i = row0 + wm*64 + f*16 + ((lane>>4)<<2) + j;
            float p = 0.f;
            if (i < ns){
                int gr = lists[i];
                int wid = (gr < TBq) ? x_wid[gr] : root_wid[gr - TBq];
                int b   = (gr < TBq) ? (gr & (Bq-1)) : (gr - TBq);
                const float* eu = EU + (size_t)wid*F32S;
                const float* tu = TU + (size_t)b*F32S;
#pragma unroll
                for (int g=0; g<2; g++){
                    int col = col0 + wn*32 + g*16 + (lane & 15);
                    if (col < Hq)
                        p += fmaxf(acc[f][g][j] + eu[col] + tu[col], 0.f) * Usf[col];
                }
            }
            p += __shfl_xor(p, 1); p += __shfl_xor(p, 2);
            p += __shfl_xor(p, 4); p += __shfl_xor(p, 8);
            if ((lane & 15) == 0 && i < ns) atomicAdd(&ss[i], p);
        }
    }
}

__global__ void stopfin_k(const int* __restrict__ ns_, const int* __restrict__ lists,
    const float* __restrict__ ss, const float* __restrict__ bUs,
    const int* __restrict__ direction, float* __restrict__ accv)
{
    const int ns = *ns_;
    int i = blockIdx.x*256 + threadIdx.x;
    float bce = 0.f, hit = 0.f, c = 0.f;
    if (i < ns){
        int gr = lists[i];
        float s = ss[i] + bUs[0];
        float stgt = (gr < TBq) ? (float)direction[gr] : 0.f;
        bce = fmaxf(s,0.f) - s*stgt + log1pf(__expf(-fabsf(s)));
        hit = ((((s >= 0.f) ? 1.f : 0.f) == stgt) ? 1.f : 0.f);
        c = 1.f;
    }
    for (int off=32; off; off>>=1){
        bce += __shfl_down(bce, off);
        hit += __shfl_down(hit, off);
        c   += __shfl_down(c,   off);
    }
    if ((threadIdx.x & 63) == 0 && c != 0.f){
        atomicAdd(&accv[3], bce);
        atomicAdd(&accv[4], hit);
        atomicAdd(&accv[5], c);
    }
}

__global__ void finalize_k(const float* __restrict__ accv, float* __restrict__ out){
    if (threadIdx.x == 0){
        out[0] = accv[0] / (float)Bq;
        out[1] = accv[3] / (float)Bq;
        out[2] = accv[1] / accv[2];
        out[3] = accv[4] / accv[5];
    }
}

extern "C" void kernel_launch(void* const* d_in, const int* in_sizes, int n_in,
                              void* d_out, int out_size, void* d_ws, size_t ws_size,
                              hipStream_t stream) {
    (void)in_sizes; (void)n_in; (void)out_size; (void)ws_size;
    const float* tree_vecs = (const float*)d_in[0];
    const int*   x_wid     = (const int*)d_in[1];
    const int*   pred_wid  = (const int*)d_in[2];
    const int*   root_wid  = (const int*)d_in[3];
    const int*   h_nei_idx = (const int*)d_in[4];
    const int*   o_nei_idx = (const int*)d_in[5];
    const int*   root_o_nei= (const int*)d_in[6];
    const int*   valid     = (const int*)d_in[7];
    const int*   direction = (const int*)d_in[8];
    const float* emb       = (const float*)d_in[9];
    const float* Wz        = (const float*)d_in[10];
    const float* bz        = (const float*)d_in[11];
    const float* Wr        = (const float*)d_in[12];
    const float* br        = (const float*)d_in[13];
    const float* Ur        = (const float*)d_in[14];
    const float* Wh        = (const float*)d_in[15];
    const float* bh        = (const float*)d_in[16];
    const float* Wm        = (const float*)d_in[17];
    const float* bW        = (const float*)d_in[18];
    const float* U         = (const float*)d_in[19];
    const float* bU        = (const float*)d_in[20];
    const float* Wo        = (const float*)d_in[21];
    const float* bWo       = (const float*)d_in[22];
    const float* Us        = (const float*)d_in[23];
    const float* bUs       = (const float*)d_in[24];

    char* w = (char*)d_ws; size_t off = 0;
    auto alloc = [&](size_t bytes)->void*{ void* p = w + off; off += (bytes + 255) & ~(size_t)255; return p; };

    ushort* hbuf  = (ushort*)alloc((size_t)Sq*HP*2);
    ushort* uhbuf = (ushort*)alloc((size_t)Sq*HP*2);
    ushort* embb  = (ushort*)alloc((size_t)896*HP*2);
    ushort* treeb = (ushort*)alloc((size_t)Bq*64*2);
    ushort* WzX   = (ushort*)alloc((size_t)512*HP*2);
    ushort* WzS   = (ushort*)alloc((size_t)512*HP*2);
    ushort* WrB   = (ushort*)alloc((size_t)512*HP*2);
    ushort* WhX   = (ushort*)alloc((size_t)512*HP*2);
    ushort* WhG   = (ushort*)alloc((size_t)512*HP*2);
    ushort* UrB   = (ushort*)alloc((size_t)512*HP*2);
    ushort* WHp   = (ushort*)alloc((size_t)512*HP*2);
    ushort* UXp   = (ushort*)alloc((size_t)512*HP*2);
    ushort* UOp   = (ushort*)alloc((size_t)512*HP*2);
    ushort* WOp   = (ushort*)alloc((size_t)832*HP*2);
    ushort* WLp   = (ushort*)alloc((size_t)512*64*2);
    ushort* ULp   = (ushort*)alloc((size_t)512*64*2);
    float*  EZ    = (float*)alloc((size_t)Vq*F32S*4);
    float*  ER    = (float*)alloc((size_t)Vq*F32S*4);
    float*  EH    = (float*)alloc((size_t)Vq*F32S*4);
    float*  EU    = (float*)alloc((size_t)Vq*F32S*4);
    float*  TP    = (float*)alloc((size_t)Bq*F32S*4);
    float*  TU    = (float*)alloc((size_t)Bq*F32S*4);
    ushort* sumh  = (ushort*)alloc((size_t)Bq*HP*2);
    ushort* gated = (ushort*)alloc((size_t)Bq*HP*2);
    ushort* nh    = (ushort*)alloc((size_t)Bq*HP*2);
    ushort* pv    = (ushort*)alloc((size_t)NPCAP*HP*2);
    float*  scores= (float*)alloc((size_t)CH2*832*4);
    float*  ss    = (float*)alloc((size_t)NSCAP*4);
    int*    listp = (int*)alloc((size_t)NPCAP*4);
    int*    lists = (int*)alloc((size_t)NSCAP*4);
    int*    meta  = (int*)alloc((size_t)(NPB*4 + 2 + 2 + 16)*4);
    int*    cnts  = meta;            // [2*NPB]
    int*    offs  = meta + 2*NPB;    // [2*NPB]
    int*    tot   = meta + 4*NPB;    // [2]
    int*    bar   = meta + 4*NPB + 2;// [2]
    float*  accv  = (float*)(meta + 4*NPB + 4);
    ushort* curo  = pv;              // stop phase reuses pv/scores region

    hipMemsetAsync(hbuf,  0, (size_t)Sq*HP*2, stream);
    hipMemsetAsync(nh,    0, (size_t)Bq*HP*2, stream);
    hipMemsetAsync(ss,    0, (size_t)NSCAP*4, stream);
    hipMemsetAsync(meta,  0, (size_t)(NPB*4 + 2 + 2 + 16)*4, stream);

    // ---- conversions (1 launch) ----
    convAll_k<<<dim3(896,14), 128, 0, stream>>>(
        emb, tree_vecs, Wz, Wr, Ur, Wh, Wm, U, Wo,
        embb, treeb, WzX, WzS, WrB, WhX, WhG, UrB, WHp, UXp, UOp, WOp, WLp, ULp);

    // ---- precomputes (2 launches) ----
    preE_k<<<dim3(8,7,4), 256, 0, stream>>>(embb, WzX, WrB, WhX, UXp,
                                            bz, br, bh, bU, EZ, ER, EH, EU);
    preT_k<<<dim3(8,4,2), 256, 0, stream>>>(treeb, WLp, ULp, bW, TP, TU);

    // ---- row compaction ----
    cnt_k <<<dim3(NPB,2), 256, 0, stream>>>(valid, direction, cnts);
    scan_k<<<1, 64, 0, stream>>>(cnts, offs, tot);
    fill_k<<<dim3(NPB,2), 256, 0, stream>>>(valid, direction, offs, listp, lists);

    // ---- persistent scan: 1 launch, 64 steps ----
    scan_coop<<<NBLK, 256, 0, stream>>>(x_wid, h_nei_idx, valid, ER, EZ, EH,
                                        WzS, WhG, UrB, hbuf, uhbuf,
                                        sumh, gated, nh, bar);

    // ---- pred phase (compacted) ----
    pred1c_k<<<dim3(8, NPCAP/128), 256, 0, stream>>>(tot, listp, hbuf, TP, WHp, pv);
    for (int c=0; c<NCH2; c++){
        int cs = c*CH2;
        pred2c_k<<<dim3(13, CH2/128), 256, 0, stream>>>(cs, tot, pv, WOp, bWo, scores);
        predred_k<<<256, 256, 0, stream>>>(cs, tot, listp, scores, pred_wid, root_wid, accv);
    }

    // ---- stop phase (compacted) ----
    curo_c<<<NSCAP, 128, 0, stream>>>(tot+1, lists, o_nei_idx, root_o_nei, hbuf, curo);
    stopc_k<<<dim3(8, NSCAP/128), 256, 0, stream>>>(tot+1, lists, x_wid, root_wid,
                                                    curo, UOp, EU, TU, Us, ss);
    stopfin_k<<<NSCAP/256, 256, 0, stream>>>(tot+1, lists, ss, bUs, direction, accv);

    finalize_k<<<1, 64, 0, stream>>>(accv, (float*)d_out);
}